// Round 12
// baseline (897.475 us; speedup 1.0000x reference)
//
#include <hip/hip_runtime.h>
#include <hip/hip_bf16.h>
#include <cmath>

// Dims
#define BATCH 128
#define SEQ 200
#define DMODEL 128
#define DINNER 256
#define DSTATE 16
#define NTOK (BATCH * SEQ)   // 25600

typedef __bf16 bf16x8 __attribute__((ext_vector_type(8)));
typedef float f32x4 __attribute__((ext_vector_type(4)));

__device__ __forceinline__ unsigned short f2bf(float f) {
  union { float f; unsigned u; } x{f};
  const unsigned r = x.u + 0x7fffu + ((x.u >> 16) & 1u);
  return (unsigned short)(r >> 16);
}
__device__ __forceinline__ float bf2f(unsigned short h) {
  union { unsigned u; float f; } x{(unsigned)h << 16};
  return x.f;
}
// Split two floats into packed-bf16 (hi, lo) planes: a ~= hi + lo.
__device__ __forceinline__ void split2(float a, float b, unsigned& hp, unsigned& lp) {
  const unsigned short ha = f2bf(a), hb = f2bf(b);
  const float ra = a - bf2f(ha), rb = b - bf2f(hb);
  hp = (unsigned)ha | ((unsigned)hb << 16);
  lp = (unsigned)f2bf(ra) | ((unsigned)f2bf(rb) << 16);
}

// DPP-fused add: v + lane_perm(v). 0xB1 = quad_perm xor1, 0x4E = quad_perm xor2.
template <int CTRL>
__device__ __forceinline__ float dpp_add(float v) {
  const int r = __builtin_amdgcn_update_dpp(0, __float_as_int(v), CTRL, 0xF, 0xF, true);
  return v + __int_as_float(r);
}

__device__ __forceinline__ float silu_f(float x) {
  return x / (1.f + __expf(-x));
}

// ---------------- LayerNorm: one wave per row of 128, f32 out ----------------
__global__ __launch_bounds__(256) void ln_kernel(const float* __restrict__ in,
                                                 const float* __restrict__ w,
                                                 const float* __restrict__ b,
                                                 float* __restrict__ out) {
  const int wv = threadIdx.x >> 6;
  const int lane = threadIdx.x & 63;
  const int row = blockIdx.x * 4 + wv;
  const float2 v = *(const float2*)(in + (size_t)row * DMODEL + lane * 2);
  float s = v.x + v.y;
#pragma unroll
  for (int o = 32; o; o >>= 1) s += __shfl_xor(s, o, 64);
  const float u = s * (1.f / 128.f);
  const float dx = v.x - u, dy = v.y - u;
  float sq = dx * dx + dy * dy;
#pragma unroll
  for (int o = 32; o; o >>= 1) sq += __shfl_xor(sq, o, 64);
  const float inv = rsqrtf(sq * (1.f / 128.f) + 1e-12f);
  const float2 wv2 = *(const float2*)(w + lane * 2);
  const float2 bv2 = *(const float2*)(b + lane * 2);
  float2 o2v;
  o2v.x = fmaf(wv2.x, dx * inv, bv2.x);
  o2v.y = fmaf(wv2.y, dy * inv, bv2.y);
  *(float2*)(out + (size_t)row * DMODEL + lane * 2) = o2v;
}

// ---------------- weight f32 -> split bf16 hi/lo planes (one layer) ----------------
__global__ __launch_bounds__(256) void wprep(const float* __restrict__ in_w,
                                             const float* __restrict__ xpwf,
                                             const float* __restrict__ xpwb,
                                             const float* __restrict__ out_w,
                                             unsigned short* __restrict__ iwH,
                                             unsigned short* __restrict__ iwL,
                                             unsigned short* __restrict__ xfH,
                                             unsigned short* __restrict__ xfL,
                                             unsigned short* __restrict__ xbH,
                                             unsigned short* __restrict__ xbL,
                                             unsigned short* __restrict__ owH,
                                             unsigned short* __restrict__ owL) {
  const int idx = blockIdx.x * 256 + threadIdx.x;  // 118784 total
  float w;
  unsigned short *H, *L;
  int off;
  if (idx < 65536)      { w = in_w[idx];        H = iwH; L = iwL; off = idx; }
  else if (idx < 75776) { w = xpwf[idx - 65536]; H = xfH; L = xfL; off = idx - 65536; }
  else if (idx < 86016) { w = xpwb[idx - 75776]; H = xbH; L = xbL; off = idx - 75776; }
  else                  { w = out_w[idx - 86016]; H = owH; L = owL; off = idx - 86016; }
  const unsigned short h = f2bf(w);
  H[off] = h;
  L[off] = f2bf(w - bf2f(h));
}

// ------- Compensated bf16 MFMA GEMM: C[M,N] = A[M,K] * W[N,K]^T (~f32 accurate) -------
// Tile 64(M) x 128(N), BK=32, 256 threads = 4 waves. A,W split hi/lo;
// product = ah*wh + al*wh + ah*wl (3 MFMAs).
// MODE 0: A = A1 (f32).
// MODE 2: dual stream via blockIdx.z (z=0: A1/Whi/Wlo/C; z=1: A2/Whi2/Wlo2/C2).
template <int MODE>
__global__ __launch_bounds__(256) void gemm_c(const float* __restrict__ A1,
                                              const float* __restrict__ A2,
                                              const unsigned short* __restrict__ Whi,
                                              const unsigned short* __restrict__ Wlo,
                                              float* __restrict__ C,
                                              const unsigned short* __restrict__ Whi2,
                                              const unsigned short* __restrict__ Wlo2,
                                              float* __restrict__ C2,
                                              int M, int N, int K) {
  __shared__ unsigned short AshH[64 * 40], AshL[64 * 40];
  __shared__ unsigned short BshH[128 * 40], BshL[128 * 40];
  const float* Ause = A1;
  const unsigned short* WH = Whi;
  const unsigned short* WL = Wlo;
  float* Cuse = C;
  if (MODE == 2 && blockIdx.z == 1) { Ause = A2; WH = Whi2; WL = Wlo2; Cuse = C2; }
  const int tid = threadIdx.x;
  const int m0 = blockIdx.y * 64;
  const int n0 = blockIdx.x * 128;
  const int lane = tid & 63;
  const int wid = tid >> 6;
  const int arow = lane & 15;
  const int kch = (lane >> 4) * 8;   // k chunk (ushort offset)
  const int bcol = wid * 32 + (lane & 15);
  f32x4 acc[4][2] = {};
  for (int k0 = 0; k0 < K; k0 += 32) {
    __syncthreads();
    {  // stage A: thread t -> row t>>2, koff (t&3)*8
      const int row = tid >> 2;
      const int koff = (tid & 3) * 8;
      const int m = m0 + row;
      float4 v0 = *(const float4*)(Ause + (size_t)m * K + k0 + koff);
      float4 v1 = *(const float4*)(Ause + (size_t)m * K + k0 + koff + 4);
      unsigned h0, l0, h1, l1, h2, l2, h3, l3;
      split2(v0.x, v0.y, h0, l0);
      split2(v0.z, v0.w, h1, l1);
      split2(v1.x, v1.y, h2, l2);
      split2(v1.z, v1.w, h3, l3);
      *(uint4*)&AshH[row * 40 + koff] = make_uint4(h0, h1, h2, h3);
      *(uint4*)&AshL[row * 40 + koff] = make_uint4(l0, l1, l2, l3);
    }
    {  // stage B: thread t -> row t>>1, koff (t&1)*16; zero rows n>=N
      const int row = tid >> 1;
      const int koff = (tid & 1) * 16;
      const int n = n0 + row;
      uint4 wh0 = make_uint4(0, 0, 0, 0), wh1 = wh0, wl0 = wh0, wl1 = wh0;
      if (n < N) {
        wh0 = *(const uint4*)(WH + (size_t)n * K + k0 + koff);
        wh1 = *(const uint4*)(WH + (size_t)n * K + k0 + koff + 8);
        wl0 = *(const uint4*)(WL + (size_t)n * K + k0 + koff);
        wl1 = *(const uint4*)(WL + (size_t)n * K + k0 + koff + 8);
      }
      *(uint4*)&BshH[row * 40 + koff] = wh0;
      *(uint4*)&BshH[row * 40 + koff + 8] = wh1;
      *(uint4*)&BshL[row * 40 + koff] = wl0;
      *(uint4*)&BshL[row * 40 + koff + 8] = wl1;
    }
    __syncthreads();
    const bf16x8 bh0 = *(const bf16x8*)&BshH[bcol * 40 + kch];
    const bf16x8 bh1 = *(const bf16x8*)&BshH[(bcol + 16) * 40 + kch];
    const bf16x8 bl0 = *(const bf16x8*)&BshL[bcol * 40 + kch];
    const bf16x8 bl1 = *(const bf16x8*)&BshL[(bcol + 16) * 40 + kch];
#pragma unroll
    for (int g = 0; g < 4; ++g) {
      const bf16x8 ah = *(const bf16x8*)&AshH[(g * 16 + arow) * 40 + kch];
      const bf16x8 al = *(const bf16x8*)&AshL[(g * 16 + arow) * 40 + kch];
      acc[g][0] = __builtin_amdgcn_mfma_f32_16x16x32_bf16(ah, bh0, acc[g][0], 0, 0, 0);
      acc[g][0] = __builtin_amdgcn_mfma_f32_16x16x32_bf16(al, bh0, acc[g][0], 0, 0, 0);
      acc[g][0] = __builtin_amdgcn_mfma_f32_16x16x32_bf16(ah, bl0, acc[g][0], 0, 0, 0);
      acc[g][1] = __builtin_amdgcn_mfma_f32_16x16x32_bf16(ah, bh1, acc[g][1], 0, 0, 0);
      acc[g][1] = __builtin_amdgcn_mfma_f32_16x16x32_bf16(al, bh1, acc[g][1], 0, 0, 0);
      acc[g][1] = __builtin_amdgcn_mfma_f32_16x16x32_bf16(ah, bl1, acc[g][1], 0, 0, 0);
    }
  }
  // epilogue: C/D layout col=lane&15, row=(lane>>4)*4+q (m89-verified)
  const int q0 = (lane >> 4) * 4;
#pragma unroll
  for (int g = 0; g < 4; ++g)
#pragma unroll
    for (int fc = 0; fc < 2; ++fc)
#pragma unroll
      for (int q = 0; q < 4; ++q) {
        const int m = m0 + g * 16 + q0 + q;
        const int n = n0 + wid * 32 + fc * 16 + (lane & 15);
        if (n < N) Cuse[(size_t)m * N + n] = acc[g][fc][q];
      }
}

// ------- Out-proj + gate + LayerNorm fused: o2 = LN((ysF+ysB)*silu(z) @ Wo^T) -------
// K=256, N=128 (full row per block -> LN is block-local). Tile 64 x 128.
__global__ __launch_bounds__(256) void gemm_oln(const float* __restrict__ A1,
                                                const float* __restrict__ A2v,
                                                const float* __restrict__ Zp,
                                                const unsigned short* __restrict__ Whi,
                                                const unsigned short* __restrict__ Wlo,
                                                const float* __restrict__ lw,
                                                const float* __restrict__ lb,
                                                float* __restrict__ o2out) {
  __shared__ unsigned short AshH[64 * 40], AshL[64 * 40];
  __shared__ unsigned short BshH[128 * 40], BshL[128 * 40];
  __shared__ float Csh[64][132];
  const int tid = threadIdx.x;
  const int m0 = blockIdx.x * 64;
  const int lane = tid & 63;
  const int wid = tid >> 6;
  const int arow = lane & 15;
  const int kch = (lane >> 4) * 8;
  const int bcol = wid * 32 + (lane & 15);
  f32x4 acc[4][2] = {};
  for (int k0 = 0; k0 < 256; k0 += 32) {
    __syncthreads();
    {  // stage A with gate
      const int row = tid >> 2;
      const int koff = (tid & 3) * 8;
      const int m = m0 + row;
      float4 v0 = *(const float4*)(A1 + (size_t)m * 256 + k0 + koff);
      float4 v1 = *(const float4*)(A1 + (size_t)m * 256 + k0 + koff + 4);
      const float4 u0 = *(const float4*)(A2v + (size_t)m * 256 + k0 + koff);
      const float4 u1 = *(const float4*)(A2v + (size_t)m * 256 + k0 + koff + 4);
      const float4 z0 = *(const float4*)(Zp + (size_t)m * 512 + k0 + koff);
      const float4 z1 = *(const float4*)(Zp + (size_t)m * 512 + k0 + koff + 4);
      v0.x = (v0.x + u0.x) * silu_f(z0.x);
      v0.y = (v0.y + u0.y) * silu_f(z0.y);
      v0.z = (v0.z + u0.z) * silu_f(z0.z);
      v0.w = (v0.w + u0.w) * silu_f(z0.w);
      v1.x = (v1.x + u1.x) * silu_f(z1.x);
      v1.y = (v1.y + u1.y) * silu_f(z1.y);
      v1.z = (v1.z + u1.z) * silu_f(z1.z);
      v1.w = (v1.w + u1.w) * silu_f(z1.w);
      unsigned h0, l0, h1, l1, h2, l2, h3, l3;
      split2(v0.x, v0.y, h0, l0);
      split2(v0.z, v0.w, h1, l1);
      split2(v1.x, v1.y, h2, l2);
      split2(v1.z, v1.w, h3, l3);
      *(uint4*)&AshH[row * 40 + koff] = make_uint4(h0, h1, h2, h3);
      *(uint4*)&AshL[row * 40 + koff] = make_uint4(l0, l1, l2, l3);
    }
    {  // stage B (N=128 full)
      const int row = tid >> 1;
      const int koff = (tid & 1) * 16;
      const uint4 wh0 = *(const uint4*)(Whi + (size_t)row * 256 + k0 + koff);
      const uint4 wh1 = *(const uint4*)(Whi + (size_t)row * 256 + k0 + koff + 8);
      const uint4 wl0 = *(const uint4*)(Wlo + (size_t)row * 256 + k0 + koff);
      const uint4 wl1 = *(const uint4*)(Wlo + (size_t)row * 256 + k0 + koff + 8);
      *(uint4*)&BshH[row * 40 + koff] = wh0;
      *(uint4*)&BshH[row * 40 + koff + 8] = wh1;
      *(uint4*)&BshL[row * 40 + koff] = wl0;
      *(uint4*)&BshL[row * 40 + koff + 8] = wl1;
    }
    __syncthreads();
    const bf16x8 bh0 = *(const bf16x8*)&BshH[bcol * 40 + kch];
    const bf16x8 bh1 = *(const bf16x8*)&BshH[(bcol + 16) * 40 + kch];
    const bf16x8 bl0 = *(const bf16x8*)&BshL[bcol * 40 + kch];
    const bf16x8 bl1 = *(const bf16x8*)&BshL[(bcol + 16) * 40 + kch];
#pragma unroll
    for (int g = 0; g < 4; ++g) {
      const bf16x8 ah = *(const bf16x8*)&AshH[(g * 16 + arow) * 40 + kch];
      const bf16x8 al = *(const bf16x8*)&AshL[(g * 16 + arow) * 40 + kch];
      acc[g][0] = __builtin_amdgcn_mfma_f32_16x16x32_bf16(ah, bh0, acc[g][0], 0, 0, 0);
      acc[g][0] = __builtin_amdgcn_mfma_f32_16x16x32_bf16(al, bh0, acc[g][0], 0, 0, 0);
      acc[g][0] = __builtin_amdgcn_mfma_f32_16x16x32_bf16(ah, bl0, acc[g][0], 0, 0, 0);
      acc[g][1] = __builtin_amdgcn_mfma_f32_16x16x32_bf16(ah, bh1, acc[g][1], 0, 0, 0);
      acc[g][1] = __builtin_amdgcn_mfma_f32_16x16x32_bf16(al, bh1, acc[g][1], 0, 0, 0);
      acc[g][1] = __builtin_amdgcn_mfma_f32_16x16x32_bf16(ah, bl1, acc[g][1], 0, 0, 0);
    }
  }
  // scatter acc into LDS (C/D layout col=lane&15, row=(lane>>4)*4+q)
  __syncthreads();
  const int q0 = (lane >> 4) * 4;
#pragma unroll
  for (int g = 0; g < 4; ++g)
#pragma unroll
    for (int fc = 0; fc < 2; ++fc)
#pragma unroll
      for (int q = 0; q < 4; ++q)
        Csh[g * 16 + q0 + q][wid * 32 + fc * 16 + (lane & 15)] = acc[g][fc][q];
  __syncthreads();
  // LayerNorm: thread -> row tid>>2, 32 cols at (tid&3)*32; quad DPP reduce.
  const int row = tid >> 2;
  const int c0 = (tid & 3) * 32;
  float vloc[32];
  float s = 0.f;
#pragma unroll
  for (int j = 0; j < 32; ++j) {
    vloc[j] = Csh[row][c0 + j];
    s += vloc[j];
  }
  s = dpp_add<0xB1>(s);
  s = dpp_add<0x4E>(s);
  const float u = s * (1.f / 128.f);
  float sq = 0.f;
#pragma unroll
  for (int j = 0; j < 32; ++j) {
    const float dd = vloc[j] - u;
    sq += dd * dd;
  }
  sq = dpp_add<0xB1>(sq);
  sq = dpp_add<0x4E>(sq);
  const float inv = rsqrtf(sq * (1.f / 128.f) + 1e-12f);
  float* outp = o2out + (size_t)(m0 + row) * 128 + c0;
#pragma unroll
  for (int j4 = 0; j4 < 8; ++j4) {
    const float4 wv = *(const float4*)(lw + c0 + j4 * 4);
    const float4 bv = *(const float4*)(lb + c0 + j4 * 4);
    float4 o;
    o.x = fmaf(wv.x, (vloc[j4 * 4 + 0] - u) * inv, bv.x);
    o.y = fmaf(wv.y, (vloc[j4 * 4 + 1] - u) * inv, bv.y);
    o.z = fmaf(wv.z, (vloc[j4 * 4 + 2] - u) * inv, bv.z);
    o.w = fmaf(wv.w, (vloc[j4 * 4 + 3] - u) * inv, bv.w);
    *(float4*)(outp + j4 * 4) = o;
  }
}

// -------- Depthwise conv + SiLU: 8 tokens/block, 7-tap sliding register window --------
__global__ __launch_bounds__(256) void conv_silu_kernel(const float* __restrict__ xz,
                                                        const float* __restrict__ cwf,
                                                        const float* __restrict__ cbf,
                                                        const float* __restrict__ cwb,
                                                        const float* __restrict__ cbb,
                                                        float* __restrict__ xcf,
                                                        float* __restrict__ xcb) {
  const int n0 = blockIdx.x * 8;
  const int l0 = n0 % SEQ;
  const int e = threadIdx.x;
  const float4 wf = *(const float4*)(cwf + e * 4);
  const float4 wb = *(const float4*)(cwb + e * 4);
  const float bfv = cbf[e], bbv = cbb[e];
  const float* px = xz + (size_t)n0 * 512 + e;
  float w[7];
#pragma unroll
  for (int j = 0; j < 6; ++j) {
    const int l = l0 - 3 + j;
    w[j] = (l >= 0 && l < SEQ) ? px[(j - 3) * 512] : 0.f;
  }
#pragma unroll
  for (int t = 0; t < 8; ++t) {
    const int l = l0 + t;
    w[6] = (l + 3 < SEQ) ? px[(t + 3) * 512] : 0.f;
    const float af = fmaf(wf.x, w[0], fmaf(wf.y, w[1], fmaf(wf.z, w[2], fmaf(wf.w, w[3], bfv))));
    const float ab = fmaf(wb.x, w[6], fmaf(wb.y, w[5], fmaf(wb.z, w[4], fmaf(wb.w, w[3], bbv))));
    xcf[(size_t)(n0 + t) * DINNER + e] = silu_f(af);
    xcb[(size_t)(n0 + t) * DINNER + e] = silu_f(ab);
#pragma unroll
    for (int j = 0; j < 6; ++j) w[j] = w[j + 1];
  }
}

// ---------------- Selective scan v7: ping-pong prefetch + fused dt-proj ----------------
// 4 states/thread. dt = softplus(dbl[:8]@dtw[d]+dtb[d]) computed in-register:
// each q-lane loads 2 of the 8 rank inputs (same 160B dbl row as B/C), 2-fma
// partial dot, quad-DPP reduce. Removes the dtsp kernel and dt array entirely.
template <int SX, int SB>
__device__ __forceinline__ void scan_body(float* __restrict__ xc,
                                          const float* __restrict__ dbl,
                                          const float* __restrict__ dtw,
                                          const float* __restrict__ dtb,
                                          const float* __restrict__ Alog,
                                          const float* __restrict__ Dp,
                                          int bb) {
  const int lane = threadIdx.x & 63;
  const int wid = threadIdx.x >> 6;
  const int q = lane & 3;
  const int dl = lane >> 2;
  const int d = blockIdx.x * 64 + wid * 16 + dl;
  const float LOG2E = 1.44269504f;
  const float4 al = *(const float4*)(Alog + d * DSTATE + q * 4);
  const float4 A2 = make_float4(-__expf(al.x) * LOG2E, -__expf(al.y) * LOG2E,
                                -__expf(al.z) * LOG2E, -__expf(al.w) * LOG2E);
  const float Dd = Dp[d];
  const float2 wq = *(const float2*)(dtw + d * 8 + q * 2);
  const float bd = dtb[d];
  const int t0 = (SX > 0) ? 0 : (SEQ - 1);
  int offX = (bb * SEQ + t0) * DINNER + d;
  int offR = (bb * SEQ + t0) * 40;          // dbl row base
  const int qb = 8 + q * 4;                  // B offset within row
  float4 h = make_float4(0.f, 0.f, 0.f, 0.f);

  float au[4]; float2 ar[4]; float4 aB[4], aC[4];
  float bu[4]; float2 br[4]; float4 bB[4], bC[4];

  auto loadg = [&](float* gu, float2* gr, float4* gB, float4* gC, int oX, int oR) {
#pragma unroll
    for (int k = 0; k < 4; ++k) {
      gu[k] = xc[oX + k * SX];
      gr[k] = *(const float2*)(dbl + oR + k * SB + q * 2);
      gB[k] = *(const float4*)(dbl + oR + k * SB + qb);
      gC[k] = *(const float4*)(dbl + oR + k * SB + qb + 16);
    }
  };
  auto computeg = [&](const float* gu, const float2* gr, const float4* gB,
                      const float4* gC, int oX) {
#pragma unroll
    for (int k = 0; k < 4; ++k) {
      float dot = fmaf(gr[k].y, wq.y, gr[k].x * wq.x);
      dot = dpp_add<0xB1>(dot);
      dot = dpp_add<0x4E>(dot);
      dot += bd;
      const float dtv = dot > 20.f ? dot : log1pf(__expf(dot));
      const float u = gu[k];
      const float du = dtv * u;
      float4 a;
      a.x = exp2f(dtv * A2.x);
      a.y = exp2f(dtv * A2.y);
      a.z = exp2f(dtv * A2.z);
      a.w = exp2f(dtv * A2.w);
      h.x = fmaf(a.x, h.x, du * gB[k].x);
      h.y = fmaf(a.y, h.y, du * gB[k].y);
      h.z = fmaf(a.z, h.z, du * gB[k].z);
      h.w = fmaf(a.w, h.w, du * gB[k].w);
      float pp = fmaf(h.w, gC[k].w, fmaf(h.z, gC[k].z, fmaf(h.y, gC[k].y, h.x * gC[k].x)));
      pp = dpp_add<0xB1>(pp);
      pp = dpp_add<0x4E>(pp);
      if (q == 0) xc[oX + k * SX] = fmaf(u, Dd, pp);
    }
  };

  loadg(au, ar, aB, aC, offX, offR);
  for (int t = 0; t < SEQ; t += 8) {
    loadg(bu, br, bB, bC, offX + 4 * SX, offR + 4 * SB);   // t+4 < SEQ always
    computeg(au, ar, aB, aC, offX);
    if (t + 8 < SEQ) loadg(au, ar, aB, aC, offX + 8 * SX, offR + 8 * SB);
    computeg(bu, br, bB, bC, offX + 4 * SX);
    offX += 8 * SX;
    offR += 8 * SB;
  }
}

__global__ __launch_bounds__(256, 4) void scan_kernel7(
    float* xcF, const float* __restrict__ dblF,
    const float* __restrict__ dtwF, const float* __restrict__ dtbF,
    const float* __restrict__ AlogF, const float* __restrict__ DF,
    float* xcB, const float* __restrict__ dblB,
    const float* __restrict__ dtwB, const float* __restrict__ dtbB,
    const float* __restrict__ AlogB, const float* __restrict__ DB) {
  if (blockIdx.z == 0)
    scan_body<DINNER, 40>(xcF, dblF, dtwF, dtbF, AlogF, DF, blockIdx.y);
  else
    scan_body<-DINNER, -40>(xcB, dblB, dtwB, dtbB, AlogB, DB, blockIdx.y);
}

// ---------------- KAN coef -> bf16 Wt[i][j][k], k = c*16+g ----------------
__global__ __launch_bounds__(256) void kan_prep(const float* __restrict__ coef,
                                                unsigned short* __restrict__ Wt) {
  const int idx = blockIdx.x * 256 + threadIdx.x;  // over 128*128*32 = 524288
  const int k = idx & 31;
  const int j = (idx >> 5) & 127;
  const int i = idx >> 12;
  const int c = k >> 4, g = k & 15;
  Wt[idx] = f2bf(coef[(((size_t)c * 128 + j) * 128 + i) * 16 + g]);
}

// ------- KAN via MFMA: 64 tokens x 128 cols, 4 waves, 2 i per barrier round -------
__global__ __launch_bounds__(256) void kan_mfma(const float* __restrict__ x,
                                                const unsigned short* __restrict__ Wt,
                                                const float* __restrict__ hin,
                                                float* __restrict__ hout,
                                                float* __restrict__ accum,
                                                int first) {
  __shared__ float Xs[128 * 64];             // [i][tok]
  __shared__ unsigned short F[2][64 * 40];   // [i-slice][tok][k], 40-padded
  __shared__ unsigned short Wsh[2][128 * 40];
  const int tid = threadIdx.x;
  const int n0 = blockIdx.x * 64;
  const int wid = tid >> 6;
  const int lane = tid & 63;
  {  // stage x transposed: 4 threads per token, 8 float4 each
    const int tok = tid & 63;
    const int cq = tid >> 6;
#pragma unroll
    for (int r = 0; r < 8; ++r) {
      const int i0 = cq * 32 + r * 4;
      const float4 v = *(const float4*)(x + (size_t)(n0 + tok) * 128 + i0);
      Xs[(i0 + 0) * 64 + tok] = v.x;
      Xs[(i0 + 1) * 64 + tok] = v.y;
      Xs[(i0 + 2) * 64 + tok] = v.z;
      Xs[(i0 + 3) * 64 + tok] = v.w;
    }
  }
  const int fs = tid >> 7;          // feature i-slice (0/1)
  const int fn = (tid & 127) >> 1;  // token 0..63
  const int fh = tid & 1;           // harmonic half: h0 = 8*fh+1
  const int wrow = tid & 127;       // W-stage row (slice = fs)
  const int arow = lane & 15;
  const int kch = (lane >> 4) * 8;
  const int bcol = wid * 32 + (lane & 15);
  f32x4 acc[4][2] = {};
  for (int ii = 0; ii < 128; ii += 2) {
    __syncthreads();
    {  // stage W for 2 i-planes: 128 threads/slice, full 64B row each
      const uint4* src = (const uint4*)(Wt + (size_t)(ii + fs) * 4096 + wrow * 32);
      uint4* dst = (uint4*)&Wsh[fs][wrow * 40];
      dst[0] = src[0]; dst[1] = src[1]; dst[2] = src[2]; dst[3] = src[3];
    }
    {  // features for token fn, i = ii+fs, harmonics 8fh+1..8fh+8 via chain
      const float xv = Xs[(ii + fs) * 64 + fn];
      const float c1 = __cosf(xv), s1 = __sinf(xv);
      float c, s;
      if (fh == 0) { c = c1; s = s1; }
      else {
        const float y = xv * 9.f;
        c = __cosf(y); s = __sinf(y);
      }
      unsigned int* Fu = (unsigned int*)F[fs];
#pragma unroll
      for (int p = 0; p < 4; ++p) {
        const float c2 = c * c1 - s * s1;
        const float s2 = s * c1 + c * s1;
        Fu[fn * 20 + fh * 4 + p]     = (unsigned)f2bf(c) | ((unsigned)f2bf(c2) << 16);
        Fu[fn * 20 + 8 + fh * 4 + p] = (unsigned)f2bf(s) | ((unsigned)f2bf(s2) << 16);
        c = c2 * c1 - s2 * s1;
        s = s2 * c1 + c2 * s1;
      }
    }
    __syncthreads();
#pragma unroll
    for (int sl = 0; sl < 2; ++sl) {
      const bf16x8 b0 = *(const bf16x8*)&Wsh[sl][bcol * 40 + kch];
      const bf16x8 b1 = *(const bf16x8*)&Wsh[sl][(bcol + 16) * 40 + kch];
#pragma unroll
      for (int g = 0; g < 4; ++g) {
        const bf16x8 a = *(const bf16x8*)&F[sl][(g * 16 + arow) * 40 + kch];
        acc[g][0] = __builtin_amdgcn_mfma_f32_16x16x32_bf16(a, b0, acc[g][0], 0, 0, 0);
        acc[g][1] = __builtin_amdgcn_mfma_f32_16x16x32_bf16(a, b1, acc[g][1], 0, 0, 0);
      }
    }
  }
  const int q0 = (lane >> 4) * 4;
#pragma unroll
  for (int g = 0; g < 4; ++g)
#pragma unroll
    for (int fc = 0; fc < 2; ++fc)
#pragma unroll
      for (int q = 0; q < 4; ++q) {
        const int n = n0 + g * 16 + q0 + q;
        const int j = wid * 32 + fc * 16 + (lane & 15);
        const size_t off = (size_t)n * 128 + j;
        const float v = acc[g][fc][q] + hin[off];
        hout[off] = v;
        const float a = 0.5f * v;
        accum[off] = first ? a : (accum[off] + a);
      }
}

extern "C" void kernel_launch(void* const* d_in, const int* in_sizes, int n_in,
                              void* d_out, int out_size, void* d_ws, size_t ws_size,
                              hipStream_t stream) {
  (void)in_sizes; (void)n_in; (void)out_size;
  const float* x     = (const float*)d_in[0];
  const float* in_w  = (const float*)d_in[1];
  const float* out_w = (const float*)d_in[2];
  const float* cwf   = (const float*)d_in[3];
  const float* cbf   = (const float*)d_in[4];
  const float* cwb   = (const float*)d_in[5];
  const float* cbb   = (const float*)d_in[6];
  const float* xpwf  = (const float*)d_in[7];
  const float* xpwb  = (const float*)d_in[8];
  const float* dtwf  = (const float*)d_in[9];
  const float* dtbf  = (const float*)d_in[10];
  const float* dtwb  = (const float*)d_in[11];
  const float* dtbb  = (const float*)d_in[12];
  const float* Alogf = (const float*)d_in[13];
  const float* Alogb = (const float*)d_in[14];
  const float* Dfp   = (const float*)d_in[15];
  const float* Dbp   = (const float*)d_in[16];
  const float* ln1w  = (const float*)d_in[17];
  const float* ln1b  = (const float*)d_in[18];
  const float* lnw   = (const float*)d_in[19];
  const float* lnb   = (const float*)d_in[20];
  const float* kanc  = (const float*)d_in[21];
  float* outp = (float*)d_out;

  // ---- workspace: static ushorts then per-token float scratch ----
  // static ushorts: Wt 2x524288 + planes 2x237568 = 1523712 -> 761856 f32
  int C = 128;
  while (C > 8) {
    const size_t need = ((size_t)761856 + (size_t)2000 * C * SEQ) * 4;
    if (need <= ws_size) break;
    C >>= 1;
  }
  const int T = C * SEQ;

  unsigned short* usbase = (unsigned short*)d_ws;
  unsigned short* Wt_l[2];
  unsigned short *iwH[2], *iwL[2], *xfH[2], *xfL[2], *xbH[2], *xbL[2], *owH[2], *owL[2];
  for (int l = 0; l < 2; ++l) {
    Wt_l[l] = usbase + (size_t)l * 524288;
    unsigned short* q = usbase + 2 * 524288 + (size_t)l * 237568;
    iwH[l] = q;           iwL[l] = q + 65536;
    xfH[l] = q + 131072;  xfL[l] = q + 141312;
    xbH[l] = q + 151552;  xbL[l] = q + 161792;
    owH[l] = q + 172032;  owL[l] = q + 204800;
  }
  float* pf = (float*)d_ws + 761856;
  float* o1   = pf; pf += (size_t)T * 128;   // ln1 out
  float* xzb  = pf; pf += (size_t)T * 512;
  float* xcf  = pf; pf += (size_t)T * 256;   // conv out fwd; scan writes ys in place
  float* xcb  = pf; pf += (size_t)T * 256;
  float* dblf = pf; pf += (size_t)T * 40;
  float* dblb = pf; pf += (size_t)T * 40;
  float* o2   = pf; pf += (size_t)T * 128;
  float* hbuf = pf; pf += (size_t)T * 128;   // chunk-local residual stream

  // ---- per-layer weight prep (once) ----
  for (int l = 0; l < 2; ++l) {
    wprep<<<464, 256, 0, stream>>>(in_w + (size_t)l * 65536, xpwf + (size_t)l * 10240,
                                   xpwb + (size_t)l * 10240, out_w + (size_t)l * 32768,
                                   iwH[l], iwL[l], xfH[l], xfL[l],
                                   xbH[l], xbL[l], owH[l], owL[l]);
    kan_prep<<<2048, 256, 0, stream>>>(kanc + (size_t)l * 2 * 128 * 128 * 16, Wt_l[l]);
  }

  for (int b0 = 0; b0 < BATCH; b0 += C) {
    const size_t tok0 = (size_t)b0 * SEQ;
    for (int l = 0; l < 2; ++l) {
      const float* hin = (l == 0) ? (x + tok0 * 128) : hbuf;
      ln_kernel<<<T / 4, 256, 0, stream>>>(hin, ln1w + l * 128, ln1b + l * 128, o1);
      gemm_c<0><<<dim3(4, T / 64), 256, 0, stream>>>(
          o1, (const float*)nullptr, iwH[l], iwL[l], xzb,
          (const unsigned short*)nullptr, (const unsigned short*)nullptr,
          (float*)nullptr, T, 512, 128);
      conv_silu_kernel<<<T / 8, 256, 0, stream>>>(xzb, cwf + l * 1024, cbf + l * 256,
                                                  cwb + l * 1024, cbb + l * 256, xcf, xcb);
      gemm_c<2><<<dim3(1, T / 64, 2), 256, 0, stream>>>(
          xcf, xcb, xfH[l], xfL[l], dblf, xbH[l], xbL[l], dblb, T, 40, 256);
      scan_kernel7<<<dim3(4, C, 2), 256, 0, stream>>>(
          xcf, dblf, dtwf + l * 2048, dtbf + l * 256, Alogf + l * 4096, Dfp + l * 256,
          xcb, dblb, dtwb + l * 2048, dtbb + l * 256, Alogb + l * 4096, Dbp + l * 256);
      gemm_oln<<<T / 64, 256, 0, stream>>>(xcf, xcb, xzb + 256, owH[l], owL[l],
                                           lnw + l * 128, lnb + l * 128, o2);
      kan_mfma<<<T / 64, 256, 0, stream>>>(o2, Wt_l[l], hin, hbuf,
                                           outp + tok0 * 128, l == 0 ? 1 : 0);
    }
  }
}

// Round 13
// 614.871 us; speedup vs baseline: 1.4596x; 1.4596x over previous
//
#include <hip/hip_runtime.h>
#include <hip/hip_bf16.h>
#include <cmath>

// Dims
#define BATCH 128
#define SEQ 200
#define DMODEL 128
#define DINNER 256
#define DSTATE 16
#define NTOK (BATCH * SEQ)   // 25600

typedef __bf16 bf16x8 __attribute__((ext_vector_type(8)));
typedef float f32x4 __attribute__((ext_vector_type(4)));

__device__ __forceinline__ unsigned short f2bf(float f) {
  union { float f; unsigned u; } x{f};
  const unsigned r = x.u + 0x7fffu + ((x.u >> 16) & 1u);
  return (unsigned short)(r >> 16);
}
__device__ __forceinline__ float bf2f(unsigned short h) {
  union { unsigned u; float f; } x{(unsigned)h << 16};
  return x.f;
}
// Split two floats into packed-bf16 (hi, lo) planes: a ~= hi + lo.
__device__ __forceinline__ void split2(float a, float b, unsigned& hp, unsigned& lp) {
  const unsigned short ha = f2bf(a), hb = f2bf(b);
  const float ra = a - bf2f(ha), rb = b - bf2f(hb);
  hp = (unsigned)ha | ((unsigned)hb << 16);
  lp = (unsigned)f2bf(ra) | ((unsigned)f2bf(rb) << 16);
}

// DPP-fused add: v + lane_perm(v). 0xB1 = quad_perm xor1, 0x4E = quad_perm xor2.
template <int CTRL>
__device__ __forceinline__ float dpp_add(float v) {
  const int r = __builtin_amdgcn_update_dpp(0, __float_as_int(v), CTRL, 0xF, 0xF, true);
  return v + __int_as_float(r);
}

__device__ __forceinline__ float silu_f(float x) {
  return x / (1.f + __expf(-x));
}

// ---------------- LayerNorm stats: one wave per row, writes (mean, inv) ----------------
__global__ __launch_bounds__(256) void ln_stats(const float* __restrict__ in,
                                                float* __restrict__ st) {
  const int wv = threadIdx.x >> 6;
  const int lane = threadIdx.x & 63;
  const int row = blockIdx.x * 4 + wv;
  const float2 v = *(const float2*)(in + (size_t)row * DMODEL + lane * 2);
  float s = v.x + v.y;
#pragma unroll
  for (int o = 32; o; o >>= 1) s += __shfl_xor(s, o, 64);
  const float u = s * (1.f / 128.f);
  const float dx = v.x - u, dy = v.y - u;
  float sq = dx * dx + dy * dy;
#pragma unroll
  for (int o = 32; o; o >>= 1) sq += __shfl_xor(sq, o, 64);
  const float inv = rsqrtf(sq * (1.f / 128.f) + 1e-12f);
  if (lane == 0) *(float2*)(st + 2 * (size_t)row) = make_float2(u, inv);
}

// ---------------- weight f32 -> split bf16 hi/lo planes (one layer) ----------------
__global__ __launch_bounds__(256) void wprep(const float* __restrict__ in_w,
                                             const float* __restrict__ xpwf,
                                             const float* __restrict__ xpwb,
                                             const float* __restrict__ out_w,
                                             unsigned short* __restrict__ iwH,
                                             unsigned short* __restrict__ iwL,
                                             unsigned short* __restrict__ xfH,
                                             unsigned short* __restrict__ xfL,
                                             unsigned short* __restrict__ xbH,
                                             unsigned short* __restrict__ xbL,
                                             unsigned short* __restrict__ owH,
                                             unsigned short* __restrict__ owL) {
  const int idx = blockIdx.x * 256 + threadIdx.x;  // 118784 total
  float w;
  unsigned short *H, *L;
  int off;
  if (idx < 65536)      { w = in_w[idx];        H = iwH; L = iwL; off = idx; }
  else if (idx < 75776) { w = xpwf[idx - 65536]; H = xfH; L = xfL; off = idx - 65536; }
  else if (idx < 86016) { w = xpwb[idx - 75776]; H = xbH; L = xbL; off = idx - 75776; }
  else                  { w = out_w[idx - 86016]; H = owH; L = owL; off = idx - 86016; }
  const unsigned short h = f2bf(w);
  H[off] = h;
  L[off] = f2bf(w - bf2f(h));
}

// ------- Compensated bf16 MFMA GEMM: C[M,N] = A[M,K] * W[N,K]^T (~f32 accurate) -------
// Tile 64(M) x 128(N), BK=32, 256 threads = 4 waves. A,W split hi/lo;
// product = ah*wh + al*wh + ah*wl (3 MFMAs).
// MODE 0: A = A1 (f32).
// MODE 1: A = LN(A1) via per-row stats (u,inv) + lw/lb per column (in-proj fused LN).
// MODE 2: dual stream via blockIdx.z (z=0: A1/Whi/Wlo/C; z=1: A2/Whi2/Wlo2/C2).
template <int MODE>
__global__ __launch_bounds__(256) void gemm_c(const float* __restrict__ A1,
                                              const float* __restrict__ A2,
                                              const float* __restrict__ stats,
                                              const float* __restrict__ lw,
                                              const float* __restrict__ lb,
                                              const unsigned short* __restrict__ Whi,
                                              const unsigned short* __restrict__ Wlo,
                                              float* __restrict__ C,
                                              const unsigned short* __restrict__ Whi2,
                                              const unsigned short* __restrict__ Wlo2,
                                              float* __restrict__ C2,
                                              int M, int N, int K) {
  __shared__ unsigned short AshH[64 * 40], AshL[64 * 40];
  __shared__ unsigned short BshH[128 * 40], BshL[128 * 40];
  const float* Ause = A1;
  const unsigned short* WH = Whi;
  const unsigned short* WL = Wlo;
  float* Cuse = C;
  if (MODE == 2 && blockIdx.z == 1) { Ause = A2; WH = Whi2; WL = Wlo2; Cuse = C2; }
  const int tid = threadIdx.x;
  const int m0 = blockIdx.y * 64;
  const int n0 = blockIdx.x * 128;
  const int lane = tid & 63;
  const int wid = tid >> 6;
  const int arow = lane & 15;
  const int kch = (lane >> 4) * 8;   // k chunk (ushort offset)
  const int bcol = wid * 32 + (lane & 15);
  f32x4 acc[4][2] = {};
  for (int k0 = 0; k0 < K; k0 += 32) {
    __syncthreads();
    {  // stage A: thread t -> row t>>2, koff (t&3)*8
      const int row = tid >> 2;
      const int koff = (tid & 3) * 8;
      const int m = m0 + row;
      float4 v0 = *(const float4*)(Ause + (size_t)m * K + k0 + koff);
      float4 v1 = *(const float4*)(Ause + (size_t)m * K + k0 + koff + 4);
      if (MODE == 1) {
        const float2 st = *(const float2*)(stats + 2 * (size_t)m);
        const float4 w0 = *(const float4*)(lw + k0 + koff);
        const float4 w1 = *(const float4*)(lw + k0 + koff + 4);
        const float4 b0 = *(const float4*)(lb + k0 + koff);
        const float4 b1 = *(const float4*)(lb + k0 + koff + 4);
        v0.x = fmaf(w0.x, (v0.x - st.x) * st.y, b0.x);
        v0.y = fmaf(w0.y, (v0.y - st.x) * st.y, b0.y);
        v0.z = fmaf(w0.z, (v0.z - st.x) * st.y, b0.z);
        v0.w = fmaf(w0.w, (v0.w - st.x) * st.y, b0.w);
        v1.x = fmaf(w1.x, (v1.x - st.x) * st.y, b1.x);
        v1.y = fmaf(w1.y, (v1.y - st.x) * st.y, b1.y);
        v1.z = fmaf(w1.z, (v1.z - st.x) * st.y, b1.z);
        v1.w = fmaf(w1.w, (v1.w - st.x) * st.y, b1.w);
      }
      unsigned h0, l0, h1, l1, h2, l2, h3, l3;
      split2(v0.x, v0.y, h0, l0);
      split2(v0.z, v0.w, h1, l1);
      split2(v1.x, v1.y, h2, l2);
      split2(v1.z, v1.w, h3, l3);
      *(uint4*)&AshH[row * 40 + koff] = make_uint4(h0, h1, h2, h3);
      *(uint4*)&AshL[row * 40 + koff] = make_uint4(l0, l1, l2, l3);
    }
    {  // stage B: thread t -> row t>>1, koff (t&1)*16; zero rows n>=N
      const int row = tid >> 1;
      const int koff = (tid & 1) * 16;
      const int n = n0 + row;
      uint4 wh0 = make_uint4(0, 0, 0, 0), wh1 = wh0, wl0 = wh0, wl1 = wh0;
      if (n < N) {
        wh0 = *(const uint4*)(WH + (size_t)n * K + k0 + koff);
        wh1 = *(const uint4*)(WH + (size_t)n * K + k0 + koff + 8);
        wl0 = *(const uint4*)(WL + (size_t)n * K + k0 + koff);
        wl1 = *(const uint4*)(WL + (size_t)n * K + k0 + koff + 8);
      }
      *(uint4*)&BshH[row * 40 + koff] = wh0;
      *(uint4*)&BshH[row * 40 + koff + 8] = wh1;
      *(uint4*)&BshL[row * 40 + koff] = wl0;
      *(uint4*)&BshL[row * 40 + koff + 8] = wl1;
    }
    __syncthreads();
    const bf16x8 bh0 = *(const bf16x8*)&BshH[bcol * 40 + kch];
    const bf16x8 bh1 = *(const bf16x8*)&BshH[(bcol + 16) * 40 + kch];
    const bf16x8 bl0 = *(const bf16x8*)&BshL[bcol * 40 + kch];
    const bf16x8 bl1 = *(const bf16x8*)&BshL[(bcol + 16) * 40 + kch];
#pragma unroll
    for (int g = 0; g < 4; ++g) {
      const bf16x8 ah = *(const bf16x8*)&AshH[(g * 16 + arow) * 40 + kch];
      const bf16x8 al = *(const bf16x8*)&AshL[(g * 16 + arow) * 40 + kch];
      acc[g][0] = __builtin_amdgcn_mfma_f32_16x16x32_bf16(ah, bh0, acc[g][0], 0, 0, 0);
      acc[g][0] = __builtin_amdgcn_mfma_f32_16x16x32_bf16(al, bh0, acc[g][0], 0, 0, 0);
      acc[g][0] = __builtin_amdgcn_mfma_f32_16x16x32_bf16(ah, bl0, acc[g][0], 0, 0, 0);
      acc[g][1] = __builtin_amdgcn_mfma_f32_16x16x32_bf16(ah, bh1, acc[g][1], 0, 0, 0);
      acc[g][1] = __builtin_amdgcn_mfma_f32_16x16x32_bf16(al, bh1, acc[g][1], 0, 0, 0);
      acc[g][1] = __builtin_amdgcn_mfma_f32_16x16x32_bf16(ah, bl1, acc[g][1], 0, 0, 0);
    }
  }
  // epilogue: C/D layout col=lane&15, row=(lane>>4)*4+q (m89-verified)
  const int q0 = (lane >> 4) * 4;
#pragma unroll
  for (int g = 0; g < 4; ++g)
#pragma unroll
    for (int fc = 0; fc < 2; ++fc)
#pragma unroll
      for (int q = 0; q < 4; ++q) {
        const int m = m0 + g * 16 + q0 + q;
        const int n = n0 + wid * 32 + fc * 16 + (lane & 15);
        if (n < N) Cuse[(size_t)m * N + n] = acc[g][fc][q];
      }
}

// ------- Out-proj + gate + LayerNorm fused: o2 = LN((ysF+ysB)*silu(z) @ Wo^T) -------
// K=256, N=128 (full row per block -> LN is block-local). Tile 64 x 128.
__global__ __launch_bounds__(256) void gemm_oln(const float* __restrict__ A1,
                                                const float* __restrict__ A2v,
                                                const float* __restrict__ Zp,
                                                const unsigned short* __restrict__ Whi,
                                                const unsigned short* __restrict__ Wlo,
                                                const float* __restrict__ lw,
                                                const float* __restrict__ lb,
                                                float* __restrict__ o2out) {
  __shared__ unsigned short AshH[64 * 40], AshL[64 * 40];
  __shared__ unsigned short BshH[128 * 40], BshL[128 * 40];
  __shared__ float Csh[64][132];
  const int tid = threadIdx.x;
  const int m0 = blockIdx.x * 64;
  const int lane = tid & 63;
  const int wid = tid >> 6;
  const int arow = lane & 15;
  const int kch = (lane >> 4) * 8;
  const int bcol = wid * 32 + (lane & 15);
  f32x4 acc[4][2] = {};
  for (int k0 = 0; k0 < 256; k0 += 32) {
    __syncthreads();
    {  // stage A with gate
      const int row = tid >> 2;
      const int koff = (tid & 3) * 8;
      const int m = m0 + row;
      float4 v0 = *(const float4*)(A1 + (size_t)m * 256 + k0 + koff);
      float4 v1 = *(const float4*)(A1 + (size_t)m * 256 + k0 + koff + 4);
      const float4 u0 = *(const float4*)(A2v + (size_t)m * 256 + k0 + koff);
      const float4 u1 = *(const float4*)(A2v + (size_t)m * 256 + k0 + koff + 4);
      const float4 z0 = *(const float4*)(Zp + (size_t)m * 512 + k0 + koff);
      const float4 z1 = *(const float4*)(Zp + (size_t)m * 512 + k0 + koff + 4);
      v0.x = (v0.x + u0.x) * silu_f(z0.x);
      v0.y = (v0.y + u0.y) * silu_f(z0.y);
      v0.z = (v0.z + u0.z) * silu_f(z0.z);
      v0.w = (v0.w + u0.w) * silu_f(z0.w);
      v1.x = (v1.x + u1.x) * silu_f(z1.x);
      v1.y = (v1.y + u1.y) * silu_f(z1.y);
      v1.z = (v1.z + u1.z) * silu_f(z1.z);
      v1.w = (v1.w + u1.w) * silu_f(z1.w);
      unsigned h0, l0, h1, l1, h2, l2, h3, l3;
      split2(v0.x, v0.y, h0, l0);
      split2(v0.z, v0.w, h1, l1);
      split2(v1.x, v1.y, h2, l2);
      split2(v1.z, v1.w, h3, l3);
      *(uint4*)&AshH[row * 40 + koff] = make_uint4(h0, h1, h2, h3);
      *(uint4*)&AshL[row * 40 + koff] = make_uint4(l0, l1, l2, l3);
    }
    {  // stage B (N=128 full)
      const int row = tid >> 1;
      const int koff = (tid & 1) * 16;
      const uint4 wh0 = *(const uint4*)(Whi + (size_t)row * 256 + k0 + koff);
      const uint4 wh1 = *(const uint4*)(Whi + (size_t)row * 256 + k0 + koff + 8);
      const uint4 wl0 = *(const uint4*)(Wlo + (size_t)row * 256 + k0 + koff);
      const uint4 wl1 = *(const uint4*)(Wlo + (size_t)row * 256 + k0 + koff + 8);
      *(uint4*)&BshH[row * 40 + koff] = wh0;
      *(uint4*)&BshH[row * 40 + koff + 8] = wh1;
      *(uint4*)&BshL[row * 40 + koff] = wl0;
      *(uint4*)&BshL[row * 40 + koff + 8] = wl1;
    }
    __syncthreads();
    const bf16x8 bh0 = *(const bf16x8*)&BshH[bcol * 40 + kch];
    const bf16x8 bh1 = *(const bf16x8*)&BshH[(bcol + 16) * 40 + kch];
    const bf16x8 bl0 = *(const bf16x8*)&BshL[bcol * 40 + kch];
    const bf16x8 bl1 = *(const bf16x8*)&BshL[(bcol + 16) * 40 + kch];
#pragma unroll
    for (int g = 0; g < 4; ++g) {
      const bf16x8 ah = *(const bf16x8*)&AshH[(g * 16 + arow) * 40 + kch];
      const bf16x8 al = *(const bf16x8*)&AshL[(g * 16 + arow) * 40 + kch];
      acc[g][0] = __builtin_amdgcn_mfma_f32_16x16x32_bf16(ah, bh0, acc[g][0], 0, 0, 0);
      acc[g][0] = __builtin_amdgcn_mfma_f32_16x16x32_bf16(al, bh0, acc[g][0], 0, 0, 0);
      acc[g][0] = __builtin_amdgcn_mfma_f32_16x16x32_bf16(ah, bl0, acc[g][0], 0, 0, 0);
      acc[g][1] = __builtin_amdgcn_mfma_f32_16x16x32_bf16(ah, bh1, acc[g][1], 0, 0, 0);
      acc[g][1] = __builtin_amdgcn_mfma_f32_16x16x32_bf16(al, bh1, acc[g][1], 0, 0, 0);
      acc[g][1] = __builtin_amdgcn_mfma_f32_16x16x32_bf16(ah, bl1, acc[g][1], 0, 0, 0);
    }
  }
  // scatter acc into LDS (C/D layout col=lane&15, row=(lane>>4)*4+q)
  __syncthreads();
  const int q0 = (lane >> 4) * 4;
#pragma unroll
  for (int g = 0; g < 4; ++g)
#pragma unroll
    for (int fc = 0; fc < 2; ++fc)
#pragma unroll
      for (int q = 0; q < 4; ++q)
        Csh[g * 16 + q0 + q][wid * 32 + fc * 16 + (lane & 15)] = acc[g][fc][q];
  __syncthreads();
  // LayerNorm: thread -> row tid>>2, 32 cols at (tid&3)*32; quad DPP reduce.
  const int row = tid >> 2;
  const int c0 = (tid & 3) * 32;
  float vloc[32];
  float s = 0.f;
#pragma unroll
  for (int j = 0; j < 32; ++j) {
    vloc[j] = Csh[row][c0 + j];
    s += vloc[j];
  }
  s = dpp_add<0xB1>(s);
  s = dpp_add<0x4E>(s);
  const float u = s * (1.f / 128.f);
  float sq = 0.f;
#pragma unroll
  for (int j = 0; j < 32; ++j) {
    const float dd = vloc[j] - u;
    sq += dd * dd;
  }
  sq = dpp_add<0xB1>(sq);
  sq = dpp_add<0x4E>(sq);
  const float inv = rsqrtf(sq * (1.f / 128.f) + 1e-12f);
  float* outp = o2out + (size_t)(m0 + row) * 128 + c0;
#pragma unroll
  for (int j4 = 0; j4 < 8; ++j4) {
    const float4 wv = *(const float4*)(lw + c0 + j4 * 4);
    const float4 bv = *(const float4*)(lb + c0 + j4 * 4);
    float4 o;
    o.x = fmaf(wv.x, (vloc[j4 * 4 + 0] - u) * inv, bv.x);
    o.y = fmaf(wv.y, (vloc[j4 * 4 + 1] - u) * inv, bv.y);
    o.z = fmaf(wv.z, (vloc[j4 * 4 + 2] - u) * inv, bv.z);
    o.w = fmaf(wv.w, (vloc[j4 * 4 + 3] - u) * inv, bv.w);
    *(float4*)(outp + j4 * 4) = o;
  }
}

// -------- Depthwise conv + SiLU: 8 tokens/block, 7-tap sliding register window --------
__global__ __launch_bounds__(256) void conv_silu_kernel(const float* __restrict__ xz,
                                                        const float* __restrict__ cwf,
                                                        const float* __restrict__ cbf,
                                                        const float* __restrict__ cwb,
                                                        const float* __restrict__ cbb,
                                                        float* __restrict__ xcf,
                                                        float* __restrict__ xcb) {
  const int n0 = blockIdx.x * 8;
  const int l0 = n0 % SEQ;
  const int e = threadIdx.x;
  const float4 wf = *(const float4*)(cwf + e * 4);
  const float4 wb = *(const float4*)(cwb + e * 4);
  const float bfv = cbf[e], bbv = cbb[e];
  const float* px = xz + (size_t)n0 * 512 + e;
  float w[7];
#pragma unroll
  for (int j = 0; j < 6; ++j) {
    const int l = l0 - 3 + j;
    w[j] = (l >= 0 && l < SEQ) ? px[(j - 3) * 512] : 0.f;
  }
#pragma unroll
  for (int t = 0; t < 8; ++t) {
    const int l = l0 + t;
    w[6] = (l + 3 < SEQ) ? px[(t + 3) * 512] : 0.f;
    const float af = fmaf(wf.x, w[0], fmaf(wf.y, w[1], fmaf(wf.z, w[2], fmaf(wf.w, w[3], bfv))));
    const float ab = fmaf(wb.x, w[6], fmaf(wb.y, w[5], fmaf(wb.z, w[4], fmaf(wb.w, w[3], bbv))));
    xcf[(size_t)(n0 + t) * DINNER + e] = silu_f(af);
    xcb[(size_t)(n0 + t) * DINNER + e] = silu_f(ab);
#pragma unroll
    for (int j = 0; j < 6; ++j) w[j] = w[j + 1];
  }
}

// ---- dt = softplus(dbl[:, :8] @ dtw^T + dtb): 8 tokens/block, fwd+bwd via grid.y ----
__global__ __launch_bounds__(256) void dtsp_kernel2(const float* __restrict__ dblF,
                                                    const float* __restrict__ dblB,
                                                    const float* __restrict__ dtwF,
                                                    const float* __restrict__ dtbF,
                                                    const float* __restrict__ dtwB,
                                                    const float* __restrict__ dtbB,
                                                    float* __restrict__ dtF,
                                                    float* __restrict__ dtB) {
  const int bwd = blockIdx.y;
  const float* __restrict__ dbl = bwd ? dblB : dblF;
  const float* __restrict__ dtw = bwd ? dtwB : dtwF;
  const float* __restrict__ dtb = bwd ? dtbB : dtbF;
  float* __restrict__ dt = bwd ? dtB : dtF;
  __shared__ float r[8][8];
  const int n0 = blockIdx.x * 8;
  const int d = threadIdx.x;
  if (threadIdx.x < 64) {
    const int tt = threadIdx.x >> 3, j = threadIdx.x & 7;
    r[tt][j] = dbl[(size_t)(n0 + tt) * 40 + j];
  }
  const float4 w0 = *(const float4*)(dtw + d * 8);
  const float4 w1 = *(const float4*)(dtw + d * 8 + 4);
  const float bd = dtb[d];
  __syncthreads();
#pragma unroll
  for (int tt = 0; tt < 8; ++tt) {
    float acc = bd;
    acc += r[tt][0] * w0.x + r[tt][1] * w0.y + r[tt][2] * w0.z + r[tt][3] * w0.w;
    acc += r[tt][4] * w1.x + r[tt][5] * w1.y + r[tt][6] * w1.z + r[tt][7] * w1.w;
    const float sp = acc > 20.f ? acc : log1pf(__expf(acc));
    dt[(size_t)(n0 + tt) * DINNER + d] = sp;
  }
}

// ---------------- Selective scan v5: ping-pong register prefetch (round-10 proven) ----
template <int SX, int SB>
__device__ __forceinline__ void scan_body(const float* __restrict__ dt,
                                          float* __restrict__ xc,
                                          const float* __restrict__ dbl,
                                          const float* __restrict__ Alog,
                                          const float* __restrict__ Dp,
                                          int bb) {
  const int lane = threadIdx.x & 63;
  const int wid = threadIdx.x >> 6;
  const int q = lane & 3;
  const int dl = lane >> 2;
  const int d = blockIdx.x * 64 + wid * 16 + dl;
  const float LOG2E = 1.44269504f;
  const float4 al = *(const float4*)(Alog + d * DSTATE + q * 4);
  const float4 A2 = make_float4(-__expf(al.x) * LOG2E, -__expf(al.y) * LOG2E,
                                -__expf(al.z) * LOG2E, -__expf(al.w) * LOG2E);
  const float Dd = Dp[d];
  const int t0 = (SX > 0) ? 0 : (SEQ - 1);
  int offX = (bb * SEQ + t0) * DINNER + d;
  int offB = (bb * SEQ + t0) * 40 + 8 + q * 4;
  float4 h = make_float4(0.f, 0.f, 0.f, 0.f);

  float adt[4], au[4]; float4 aB[4], aC[4];
  float bdt[4], bu[4]; float4 bB[4], bC[4];

  auto loadg = [&](float* gdt, float* gu, float4* gB, float4* gC, int oX, int oB) {
#pragma unroll
    for (int k = 0; k < 4; ++k) {
      gdt[k] = dt[oX + k * SX];
      gu[k] = xc[oX + k * SX];
      gB[k] = *(const float4*)(dbl + oB + k * SB);
      gC[k] = *(const float4*)(dbl + oB + k * SB + 16);
    }
  };
  auto computeg = [&](const float* gdt, const float* gu, const float4* gB,
                      const float4* gC, int oX) {
#pragma unroll
    for (int k = 0; k < 4; ++k) {
      const float dtv = gdt[k];
      const float u = gu[k];
      const float du = dtv * u;
      float4 a;
      a.x = exp2f(dtv * A2.x);
      a.y = exp2f(dtv * A2.y);
      a.z = exp2f(dtv * A2.z);
      a.w = exp2f(dtv * A2.w);
      h.x = fmaf(a.x, h.x, du * gB[k].x);
      h.y = fmaf(a.y, h.y, du * gB[k].y);
      h.z = fmaf(a.z, h.z, du * gB[k].z);
      h.w = fmaf(a.w, h.w, du * gB[k].w);
      float pp = fmaf(h.w, gC[k].w, fmaf(h.z, gC[k].z, fmaf(h.y, gC[k].y, h.x * gC[k].x)));
      pp = dpp_add<0xB1>(pp);
      pp = dpp_add<0x4E>(pp);
      if (q == 0) xc[oX + k * SX] = fmaf(u, Dd, pp);
    }
  };

  loadg(adt, au, aB, aC, offX, offB);
  for (int t = 0; t < SEQ; t += 8) {
    loadg(bdt, bu, bB, bC, offX + 4 * SX, offB + 4 * SB);   // t+4 < SEQ always
    computeg(adt, au, aB, aC, offX);
    if (t + 8 < SEQ) loadg(adt, au, aB, aC, offX + 8 * SX, offB + 8 * SB);
    computeg(bdt, bu, bB, bC, offX + 4 * SX);
    offX += 8 * SX;
    offB += 8 * SB;
  }
}

__global__ __launch_bounds__(256, 4) void scan_kernel5(
    const float* __restrict__ dtF, float* xcF, const float* __restrict__ dblF,
    const float* __restrict__ AlogF, const float* __restrict__ DF,
    const float* __restrict__ dtB, float* xcB, const float* __restrict__ dblB,
    const float* __restrict__ AlogB, const float* __restrict__ DB) {
  if (blockIdx.z == 0)
    scan_body<DINNER, 40>(dtF, xcF, dblF, AlogF, DF, blockIdx.y);
  else
    scan_body<-DINNER, -40>(dtB, xcB, dblB, AlogB, DB, blockIdx.y);
}

// ---------------- KAN coef -> bf16 Wt[i][j][k], k = c*16+g ----------------
__global__ __launch_bounds__(256) void kan_prep(const float* __restrict__ coef,
                                                unsigned short* __restrict__ Wt) {
  const int idx = blockIdx.x * 256 + threadIdx.x;  // over 128*128*32 = 524288
  const int k = idx & 31;
  const int j = (idx >> 5) & 127;
  const int i = idx >> 12;
  const int c = k >> 4, g = k & 15;
  Wt[idx] = f2bf(coef[(((size_t)c * 128 + j) * 128 + i) * 16 + g]);
}

// ------- KAN via MFMA: 64 tokens x 128 cols, 4 waves, 2 i per barrier round -------
__global__ __launch_bounds__(256) void kan_mfma(const float* __restrict__ x,
                                                const unsigned short* __restrict__ Wt,
                                                const float* __restrict__ hin,
                                                float* __restrict__ hout,
                                                float* __restrict__ accum,
                                                int first) {
  __shared__ float Xs[128 * 64];             // [i][tok]
  __shared__ unsigned short F[2][64 * 40];   // [i-slice][tok][k], 40-padded
  __shared__ unsigned short Wsh[2][128 * 40];
  const int tid = threadIdx.x;
  const int n0 = blockIdx.x * 64;
  const int wid = tid >> 6;
  const int lane = tid & 63;
  {  // stage x transposed: 4 threads per token, 8 float4 each
    const int tok = tid & 63;
    const int cq = tid >> 6;
#pragma unroll
    for (int r = 0; r < 8; ++r) {
      const int i0 = cq * 32 + r * 4;
      const float4 v = *(const float4*)(x + (size_t)(n0 + tok) * 128 + i0);
      Xs[(i0 + 0) * 64 + tok] = v.x;
      Xs[(i0 + 1) * 64 + tok] = v.y;
      Xs[(i0 + 2) * 64 + tok] = v.z;
      Xs[(i0 + 3) * 64 + tok] = v.w;
    }
  }
  const int fs = tid >> 7;          // feature i-slice (0/1)
  const int fn = (tid & 127) >> 1;  // token 0..63
  const int fh = tid & 1;           // harmonic half: h0 = 8*fh+1
  const int wrow = tid & 127;       // W-stage row (slice = fs)
  const int arow = lane & 15;
  const int kch = (lane >> 4) * 8;
  const int bcol = wid * 32 + (lane & 15);
  f32x4 acc[4][2] = {};
  for (int ii = 0; ii < 128; ii += 2) {
    __syncthreads();
    {  // stage W for 2 i-planes: 128 threads/slice, full 64B row each
      const uint4* src = (const uint4*)(Wt + (size_t)(ii + fs) * 4096 + wrow * 32);
      uint4* dst = (uint4*)&Wsh[fs][wrow * 40];
      dst[0] = src[0]; dst[1] = src[1]; dst[2] = src[2]; dst[3] = src[3];
    }
    {  // features for token fn, i = ii+fs, harmonics 8fh+1..8fh+8 via chain
      const float xv = Xs[(ii + fs) * 64 + fn];
      const float c1 = __cosf(xv), s1 = __sinf(xv);
      float c, s;
      if (fh == 0) { c = c1; s = s1; }
      else {
        const float y = xv * 9.f;
        c = __cosf(y); s = __sinf(y);
      }
      unsigned int* Fu = (unsigned int*)F[fs];
#pragma unroll
      for (int p = 0; p < 4; ++p) {
        const float c2 = c * c1 - s * s1;
        const float s2 = s * c1 + c * s1;
        Fu[fn * 20 + fh * 4 + p]     = (unsigned)f2bf(c) | ((unsigned)f2bf(c2) << 16);
        Fu[fn * 20 + 8 + fh * 4 + p] = (unsigned)f2bf(s) | ((unsigned)f2bf(s2) << 16);
        c = c2 * c1 - s2 * s1;
        s = s2 * c1 + c2 * s1;
      }
    }
    __syncthreads();
#pragma unroll
    for (int sl = 0; sl < 2; ++sl) {
      const bf16x8 b0 = *(const bf16x8*)&Wsh[sl][bcol * 40 + kch];
      const bf16x8 b1 = *(const bf16x8*)&Wsh[sl][(bcol + 16) * 40 + kch];
#pragma unroll
      for (int g = 0; g < 4; ++g) {
        const bf16x8 a = *(const bf16x8*)&F[sl][(g * 16 + arow) * 40 + kch];
        acc[g][0] = __builtin_amdgcn_mfma_f32_16x16x32_bf16(a, b0, acc[g][0], 0, 0, 0);
        acc[g][1] = __builtin_amdgcn_mfma_f32_16x16x32_bf16(a, b1, acc[g][1], 0, 0, 0);
      }
    }
  }
  const int q0 = (lane >> 4) * 4;
#pragma unroll
  for (int g = 0; g < 4; ++g)
#pragma unroll
    for (int fc = 0; fc < 2; ++fc)
#pragma unroll
      for (int q = 0; q < 4; ++q) {
        const int n = n0 + g * 16 + q0 + q;
        const int j = wid * 32 + fc * 16 + (lane & 15);
        const size_t off = (size_t)n * 128 + j;
        const float v = acc[g][fc][q] + hin[off];
        hout[off] = v;
        const float a = 0.5f * v;
        accum[off] = first ? a : (accum[off] + a);
      }
}

extern "C" void kernel_launch(void* const* d_in, const int* in_sizes, int n_in,
                              void* d_out, int out_size, void* d_ws, size_t ws_size,
                              hipStream_t stream) {
  (void)in_sizes; (void)n_in; (void)out_size;
  const float* x     = (const float*)d_in[0];
  const float* in_w  = (const float*)d_in[1];
  const float* out_w = (const float*)d_in[2];
  const float* cwf   = (const float*)d_in[3];
  const float* cbf   = (const float*)d_in[4];
  const float* cwb   = (const float*)d_in[5];
  const float* cbb   = (const float*)d_in[6];
  const float* xpwf  = (const float*)d_in[7];
  const float* xpwb  = (const float*)d_in[8];
  const float* dtwf  = (const float*)d_in[9];
  const float* dtbf  = (const float*)d_in[10];
  const float* dtwb  = (const float*)d_in[11];
  const float* dtbb  = (const float*)d_in[12];
  const float* Alogf = (const float*)d_in[13];
  const float* Alogb = (const float*)d_in[14];
  const float* Dfp   = (const float*)d_in[15];
  const float* Dbp   = (const float*)d_in[16];
  const float* ln1w  = (const float*)d_in[17];
  const float* ln1b  = (const float*)d_in[18];
  const float* lnw   = (const float*)d_in[19];
  const float* lnb   = (const float*)d_in[20];
  const float* kanc  = (const float*)d_in[21];
  float* outp = (float*)d_out;

  // ---- workspace: static ushorts then per-token float scratch ----
  // static ushorts: Wt 2x524288 + planes 2x237568 = 1523712 -> 761856 f32
  int C = 128;
  while (C > 8) {
    const size_t need = ((size_t)761856 + (size_t)2000 * C * SEQ) * 4;
    if (need <= ws_size) break;
    C >>= 1;
  }
  const int T = C * SEQ;

  unsigned short* usbase = (unsigned short*)d_ws;
  unsigned short* Wt_l[2];
  unsigned short *iwH[2], *iwL[2], *xfH[2], *xfL[2], *xbH[2], *xbL[2], *owH[2], *owL[2];
  for (int l = 0; l < 2; ++l) {
    Wt_l[l] = usbase + (size_t)l * 524288;
    unsigned short* q = usbase + 2 * 524288 + (size_t)l * 237568;
    iwH[l] = q;           iwL[l] = q + 65536;
    xfH[l] = q + 131072;  xfL[l] = q + 141312;
    xbH[l] = q + 151552;  xbL[l] = q + 161792;
    owH[l] = q + 172032;  owL[l] = q + 204800;
  }
  float* pf = (float*)d_ws + 761856;
  float* stats = pf; pf += (size_t)T * 2;    // ln1 (mean, inv) per row
  float* xzb  = pf; pf += (size_t)T * 512;
  float* xcf  = pf; pf += (size_t)T * 256;   // conv out fwd; scan writes ys in place
  float* xcb  = pf; pf += (size_t)T * 256;
  float* dblf = pf; pf += (size_t)T * 40;
  float* dblb = pf; pf += (size_t)T * 40;
  float* dtf  = pf; pf += (size_t)T * 256;
  float* dtb  = pf; pf += (size_t)T * 256;
  float* o2   = pf; pf += (size_t)T * 128;
  float* hbuf = pf; pf += (size_t)T * 128;   // chunk-local residual stream

  // ---- per-layer weight prep (once) ----
  for (int l = 0; l < 2; ++l) {
    wprep<<<464, 256, 0, stream>>>(in_w + (size_t)l * 65536, xpwf + (size_t)l * 10240,
                                   xpwb + (size_t)l * 10240, out_w + (size_t)l * 32768,
                                   iwH[l], iwL[l], xfH[l], xfL[l],
                                   xbH[l], xbL[l], owH[l], owL[l]);
    kan_prep<<<2048, 256, 0, stream>>>(kanc + (size_t)l * 2 * 128 * 128 * 16, Wt_l[l]);
  }

  for (int b0 = 0; b0 < BATCH; b0 += C) {
    const size_t tok0 = (size_t)b0 * SEQ;
    for (int l = 0; l < 2; ++l) {
      const float* hin = (l == 0) ? (x + tok0 * 128) : hbuf;
      ln_stats<<<T / 4, 256, 0, stream>>>(hin, stats);
      gemm_c<1><<<dim3(4, T / 64), 256, 0, stream>>>(
          hin, (const float*)nullptr, stats, ln1w + l * 128, ln1b + l * 128,
          iwH[l], iwL[l], xzb,
          (const unsigned short*)nullptr, (const unsigned short*)nullptr,
          (float*)nullptr, T, 512, 128);
      conv_silu_kernel<<<T / 8, 256, 0, stream>>>(xzb, cwf + l * 1024, cbf + l * 256,
                                                  cwb + l * 1024, cbb + l * 256, xcf, xcb);
      gemm_c<2><<<dim3(1, T / 64, 2), 256, 0, stream>>>(
          xcf, xcb, (const float*)nullptr, (const float*)nullptr, (const float*)nullptr,
          xfH[l], xfL[l], dblf, xbH[l], xbL[l], dblb, T, 40, 256);
      dtsp_kernel2<<<dim3(T / 8, 2), 256, 0, stream>>>(dblf, dblb,
                                                       dtwf + l * 2048, dtbf + l * 256,
                                                       dtwb + l * 2048, dtbb + l * 256,
                                                       dtf, dtb);
      scan_kernel5<<<dim3(4, C, 2), 256, 0, stream>>>(
          dtf, xcf, dblf, Alogf + l * 4096, Dfp + l * 256,
          dtb, xcb, dblb, Alogb + l * 4096, Dbp + l * 256);
      gemm_oln<<<T / 64, 256, 0, stream>>>(xcf, xcb, xzb + 256, owH[l], owL[l],
                                           lnw + l * 128, lnb + l * 128, o2);
      kan_mfma<<<T / 64, 256, 0, stream>>>(o2, Wt_l[l], hin, hbuf,
                                           outp + tok0 * 128, l == 0 ? 1 : 0);
    }
  }
}